// Round 6
// baseline (96.909 us; speedup 1.0000x reference)
//
#include <hip/hip_runtime.h>

typedef unsigned int   uint32;
typedef unsigned short ushort16;

constexpr int BATCH = 2;
constexpr int SEQ   = 2048;
constexpr int DM    = 512;
constexpr int NH    = 8;
constexpr int DP    = 64;
constexpr int MROWS = BATCH * SEQ;                              // 4096
constexpr size_t HEADS_ELEMS = (size_t)BATCH * NH * SEQ * DP;   // 2,097,152

typedef short bf16x8 __attribute__((ext_vector_type(8)));
typedef float f32x4  __attribute__((ext_vector_type(4)));
typedef float f32x16 __attribute__((ext_vector_type(16)));
#define MFMA16(a, b, c) __builtin_amdgcn_mfma_f32_16x16x32_bf16((a), (b), (c), 0, 0, 0)
#define MFMA32(a, b, c) __builtin_amdgcn_mfma_f32_32x32x16_bf16((a), (b), (c), 0, 0, 0)

__device__ __forceinline__ ushort16 f2bf(float f) {
    uint32 u = __float_as_uint(f);
    uint32 r = (u + 0x7fffu + ((u >> 16) & 1u)) >> 16;
    return (ushort16)r;
}

__device__ __forceinline__ uint32 cvtpk(float a, float b) {
    uint32 r;
    asm("v_cvt_pk_bf16_f32 %0, %1, %2" : "=v"(r) : "v"(a), "v"(b));
    return r;
}

__device__ __forceinline__ bf16x8 mkfrag(uint32 u0, uint32 u1, uint32 u2, uint32 u3) {
    union { uint32 u[4]; bf16x8 v; } t;
    t.u[0] = u0; t.u[1] = u1; t.u[2] = u2; t.u[3] = u3;
    return t.v;
}

__device__ __forceinline__ void gload16(const void* g, void* l) {
    __builtin_amdgcn_global_load_lds(
        (const __attribute__((address_space(1))) unsigned int*)g,
        (__attribute__((address_space(3))) unsigned int*)l, 16, 0, 0);
}

// ---------------------------------------------------------------------------
// Convert fp32 inputs to bf16 working buffers.
// ---------------------------------------------------------------------------
constexpr int XF4 = (MROWS * DM) / 4;   // 524288
constexpr int WF4 = (DM * DM) / 4;      // 65536

__global__ __launch_bounds__(256)
void convert_inputs(const float4* __restrict__ x,  const float4* __restrict__ wq,
                    const float4* __restrict__ wk, const float4* __restrict__ wv,
                    const float4* __restrict__ wo, ushort4* __restrict__ xb,
                    ushort4* __restrict__ wqkv, ushort4* __restrict__ wob) {
    const int idx = blockIdx.x * 256 + threadIdx.x;
    float4 v; ushort4* dp;
    if (idx < XF4) { v = x[idx]; dp = xb + idx; }
    else {
        const int r = idx - XF4;
        if (r < WF4)          { v = wq[r];           dp = wqkv + r; }
        else if (r < 2 * WF4) { v = wk[r - WF4];     dp = wqkv + r; }
        else if (r < 3 * WF4) { v = wv[r - 2 * WF4]; dp = wqkv + r; }
        else                  { v = wo[r - 3 * WF4]; dp = wob + (r - 3 * WF4); }
    }
    ushort4 o = {f2bf(v.x), f2bf(v.y), f2bf(v.z), f2bf(v.w)};
    *dp = o;
}

// ---------------------------------------------------------------------------
// bf16 MFMA GEMM (unchanged; correctness-verified).
// ---------------------------------------------------------------------------
template <int BM, int BN, int EPI>
__global__ __launch_bounds__(256)
void gemm_mfma(const ushort16* __restrict__ X, const ushort16* __restrict__ Wc,
               const float* __restrict__ bq_, const float* __restrict__ bk_,
               const float* __restrict__ bv_, const float* __restrict__ bo_,
               ushort16* __restrict__ Qh, ushort16* __restrict__ Kh,
               ushort16* __restrict__ Vt, float* __restrict__ Out) {
    constexpr int FM = BM / 32;
    constexpr int FN = BN / 32;
    __shared__ ushort16 As[BM * 32];
    __shared__ ushort16 Bs[BN * 32];

    const int tid  = threadIdx.x;
    const int lane = tid & 63;
    const int wid  = tid >> 6;
    const int lg   = lane >> 4;
    const int lq   = lane & 15;
    const int wr   = wid >> 1;
    const int wc   = wid & 1;
    const int m0   = blockIdx.y * BM;
    const int n0   = blockIdx.x * BN;
    const bool swapped = (EPI == 1) || (n0 < 2 * DM);

    f32x4 acc[FM][FN];
    #pragma unroll
    for (int i = 0; i < FM; i++)
        #pragma unroll
        for (int j = 0; j < FN; j++)
            #pragma unroll
            for (int r = 0; r < 4; r++) acc[i][j][r] = 0.f;

    for (int k0 = 0; k0 < DM; k0 += 32) {
        #pragma unroll
        for (int i = 0; i < BM / 64; i++) {
            const int ch = tid + i * 256;
            const int row = ch >> 2, c8 = (ch & 3) * 8;
            gload16(X + (size_t)(m0 + row) * DM + k0 + c8, As + (size_t)ch * 8);
        }
        #pragma unroll
        for (int i = 0; i < BN / 64; i++) {
            const int ch = tid + i * 256;
            const int row = ch >> 2, c8 = (ch & 3) * 8;
            gload16(Wc + (size_t)(n0 + row) * DM + k0 + c8, Bs + (size_t)ch * 8);
        }
        __syncthreads();

        bf16x8 af[FM], bfr[FN];
        #pragma unroll
        for (int i = 0; i < FM; i++)
            af[i] = *(const bf16x8*)(As + (size_t)(wr * (BM / 2) + i * 16 + lq) * 32 + lg * 8);
        #pragma unroll
        for (int j = 0; j < FN; j++)
            bfr[j] = *(const bf16x8*)(Bs + (size_t)(wc * (BN / 2) + j * 16 + lq) * 32 + lg * 8);

        if (swapped) {
            #pragma unroll
            for (int i = 0; i < FM; i++)
                #pragma unroll
                for (int j = 0; j < FN; j++)
                    acc[i][j] = MFMA16(bfr[j], af[i], acc[i][j]);
        } else {
            #pragma unroll
            for (int i = 0; i < FM; i++)
                #pragma unroll
                for (int j = 0; j < FN; j++)
                    acc[i][j] = MFMA16(af[i], bfr[j], acc[i][j]);
        }
        __syncthreads();
    }

    if (EPI == 1) {
        #pragma unroll
        for (int i = 0; i < FM; i++) {
            const int m = m0 + wr * (BM / 2) + i * 16 + lq;
            #pragma unroll
            for (int j = 0; j < FN; j++) {
                const int nr = n0 + wc * (BN / 2) + j * 16 + lg * 4;
                float4 b4 = *(const float4*)(bo_ + nr);
                float4 o;
                o.x = acc[i][j][0] + b4.x; o.y = acc[i][j][1] + b4.y;
                o.z = acc[i][j][2] + b4.z; o.w = acc[i][j][3] + b4.w;
                *(float4*)(Out + (size_t)m * DM + nr) = o;
            }
        }
    } else if (n0 < 2 * DM) {
        #pragma unroll
        for (int i = 0; i < FM; i++) {
            const int m = m0 + wr * (BM / 2) + i * 16 + lq;
            const int b = m >> 11, s = m & (SEQ - 1);
            #pragma unroll
            for (int j = 0; j < FN; j++) {
                const int nr = n0 + wc * (BN / 2) + j * 16 + lg * 4;
                const bool isq = nr < DM;
                const int rel = nr & (DM - 1);
                const int h = rel >> 6, d = rel & 63;
                float4 b4 = *(const float4*)((isq ? bq_ : bk_) + rel);
                const float sc = isq ? 0.125f : 1.0f;
                ushort4 o = { f2bf((acc[i][j][0] + b4.x) * sc),
                              f2bf((acc[i][j][1] + b4.y) * sc),
                              f2bf((acc[i][j][2] + b4.z) * sc),
                              f2bf((acc[i][j][3] + b4.w) * sc) };
                ushort16* dst = (isq ? Qh : Kh) +
                    (((size_t)(b * NH + h) * SEQ + s) * DP + d);
                *(ushort4*)dst = o;
            }
        }
    } else {
        #pragma unroll
        for (int j = 0; j < FN; j++) {
            const int n = n0 + wc * (BN / 2) + j * 16 + lq;
            const int rel = n - 2 * DM;
            const int h = rel >> 6, d = rel & 63;
            const float bias = bv_[rel];
            #pragma unroll
            for (int i = 0; i < FM; i++) {
                const int mr = m0 + wr * (BM / 2) + i * 16 + lg * 4;
                const int b = mr >> 11, s0 = mr & (SEQ - 1);
                ushort4 o = { f2bf(acc[i][j][0] + bias),
                              f2bf(acc[i][j][1] + bias),
                              f2bf(acc[i][j][2] + bias),
                              f2bf(acc[i][j][3] + bias) };
                ushort16* dst = Vt +
                    (((size_t)(b * NH + h) * DP + d) * SEQ + s0);
                *(ushort4*)dst = o;
            }
        }
    }
}

// ---------------------------------------------------------------------------
// MFMA bf16 flash attention v4 (32x32 shapes, m214-style).
// Grid 256 (XCD-swizzled 8x32, 1 block/CU): block = 128 q-rows of one (b,h).
// 4 waves x 32 q-rows each, full k-range. Swapped QK^T with 32x32x16 MFMA:
// lane owns P-row slice (q=lane&31, 32 of 64 k per lane) fully in registers;
// PV A-fragments built via cvt_pk + shfl_xor(32) -- NO P through LDS.
// K/V tiles (64) double-buffered, XOR-swizzled, counted vmcnt(4) pipeline
// (vmcnt(0) only at the last tile). Defer-max THR=8.
// ---------------------------------------------------------------------------
__global__ __launch_bounds__(256, 1)
void attn_mfma(const ushort16* __restrict__ Q, const ushort16* __restrict__ K,
               const ushort16* __restrict__ Vt, ushort16* __restrict__ O) {
    __shared__ ushort16 Kl[2][64 * 64];   // 8 KB each
    __shared__ ushort16 Vl[2][64 * 64];

    const int tid  = threadIdx.x;
    const int lane = tid & 63;
    const int wid  = tid >> 6;
    const int h    = lane >> 5;          // lane half
    const int l31  = lane & 31;
    const int l7   = l31 & 7;

    const int bid = blockIdx.x;                   // 0..255
    const int w   = (bid & 7) * 32 + (bid >> 3);  // 8 XCDs x 32 = 2 heads/XCD
    const int qt  = w & 15;                       // q-tile (128 rows)
    const int bh  = w >> 4;                       // head 0..15

    // Q fragments (B-operand: lane holds col q=l31, k = h*8+j per 16-depth step)
    const int qrow = qt * 128 + wid * 32 + l31;
    const ushort16* qbase = Q + ((size_t)bh * SEQ + qrow) * DP;
    bf16x8 qf[4];
    #pragma unroll
    for (int ds = 0; ds < 4; ds++)
        qf[ds] = *(const bf16x8*)(qbase + ds * 16 + h * 8);

    f32x16 ok0, ok1;
    #pragma unroll
    for (int r = 0; r < 16; r++) { ok0[r] = 0.f; ok1[r] = 0.f; }
    float mrun = -1e30f, lrun = 0.f;

    // ---- staging (linear LDS dest, inverse-swizzled global source) ----
    const ushort16* kg = K  + (size_t)bh * SEQ * DP;   // [2048][64]
    const ushort16* vg = Vt + (size_t)bh * DP * SEQ;   // [64][2048]
    const int r0 = tid >> 3, c0 = tid & 7;
    const int sc0 = (c0 ^ (r0 & 7)) * 8;
    const int r1 = r0 + 32;
    const int sc1 = (c0 ^ (r1 & 7)) * 8;
    const ushort16* kp0 = kg + (size_t)r0 * DP + sc0;
    const ushort16* kp1 = kg + (size_t)r1 * DP + sc1;
    const ushort16* vp0 = vg + (size_t)r0 * SEQ + sc0;
    const ushort16* vp1 = vg + (size_t)r1 * SEQ + sc1;
    ushort16* const kA0 = &Kl[0][(size_t)tid * 8];
    ushort16* const kA1 = &Kl[0][(size_t)(tid + 256) * 8];
    ushort16* const kB0 = &Kl[1][(size_t)tid * 8];
    ushort16* const kB1 = &Kl[1][(size_t)(tid + 256) * 8];
    ushort16* const vA0 = &Vl[0][(size_t)tid * 8];
    ushort16* const vA1 = &Vl[0][(size_t)(tid + 256) * 8];
    ushort16* const vB0 = &Vl[1][(size_t)tid * 8];
    ushort16* const vB1 = &Vl[1][(size_t)(tid + 256) * 8];

    auto stageA = [&]() {
        gload16(kp0, kA0); gload16(kp1, kA1);
        gload16(vp0, vA0); gload16(vp1, vA1);
        kp0 += 64 * DP; kp1 += 64 * DP; vp0 += 64; vp1 += 64;
    };
    auto stageB = [&]() {
        gload16(kp0, kB0); gload16(kp1, kB1);
        gload16(vp0, vB0); gload16(vp1, vB1);
        kp0 += 64 * DP; kp1 += 64 * DP; vp0 += 64; vp1 += 64;
    };

    // hoisted swizzled read offsets: chunk (ds*2+h) of row (base + l31)
    const int rb0 = l31 * 64;            // rows 0..31 of tile
    const int rb1 = rb0 + 32 * 64;       // rows 32..63
    int koff[4];
    #pragma unroll
    for (int ds = 0; ds < 4; ds++)
        koff[ds] = ((ds * 2 + h) ^ l7) * 8;

    const ushort16* const kbA = &Kl[0][0];
    const ushort16* const kbB = &Kl[1][0];
    const ushort16* const vbA = &Vl[0][0];
    const ushort16* const vbB = &Vl[1][0];

    auto compute = [&](const ushort16* kb, const ushort16* vb) {
        // ---- S^T tiles: st0 = k 0..31, st1 = k 32..63 (lane: q=l31) ----
        f32x16 st0, st1;
        #pragma unroll
        for (int r = 0; r < 16; r++) { st0[r] = 0.f; st1[r] = 0.f; }
        __builtin_amdgcn_s_setprio(1);
        #pragma unroll
        for (int ds = 0; ds < 4; ds++) {
            bf16x8 kf = *(const bf16x8*)(kb + rb0 + koff[ds]);
            st0 = MFMA32(kf, qf[ds], st0);
        }
        #pragma unroll
        for (int ds = 0; ds < 4; ds++) {
            bf16x8 kf = *(const bf16x8*)(kb + rb1 + koff[ds]);
            st1 = MFMA32(kf, qf[ds], st1);
        }
        __builtin_amdgcn_s_setprio(0);

        // ---- online softmax, lane-local (q = l31), halves combined by shfl
        float tmax = st0[0];
        #pragma unroll
        for (int r = 1; r < 16; r++) tmax = fmaxf(tmax, st0[r]);
        #pragma unroll
        for (int r = 0; r < 16; r++) tmax = fmaxf(tmax, st1[r]);
        tmax = fmaxf(tmax, __shfl_xor(tmax, 32));

        if (!__all(tmax <= mrun + 8.f)) {       // defer-max, rare
            const float mnew = fmaxf(mrun, tmax);
            const float corr = __expf(mrun - mnew);
            #pragma unroll
            for (int r = 0; r < 16; r++) {
                const float c = __shfl(corr, (r & 3) + 8 * (r >> 2) + 4 * h);
                ok0[r] *= c; ok1[r] *= c;
            }
            lrun *= corr;
            mrun = mnew;
        }

        float psum = 0.f;
        #pragma unroll
        for (int r = 0; r < 16; r++) {
            st0[r] = __expf(st0[r] - mrun); psum += st0[r];
            st1[r] = __expf(st1[r] - mrun); psum += st1[r];
        }
        psum += __shfl_xor(psum, 32);
        lrun += psum;

        // ---- pack P to bf16 A-fragments (cvt_pk + half-swap via shfl_xor 32)
        uint32 A0 = cvtpk(st0[0], st0[1]),  A1 = cvtpk(st0[2], st0[3]);
        uint32 B0 = cvtpk(st0[4], st0[5]),  B1 = cvtpk(st0[6], st0[7]);
        uint32 C0 = cvtpk(st0[8], st0[9]),  C1 = cvtpk(st0[10], st0[11]);
        uint32 D0 = cvtpk(st0[12], st0[13]), D1 = cvtpk(st0[14], st0[15]);
        uint32 z0 = __shfl_xor((int)(h ? A0 : B0), 32);
        uint32 z1 = __shfl_xor((int)(h ? A1 : B1), 32);
        uint32 z2 = __shfl_xor((int)(h ? C0 : D0), 32);
        uint32 z3 = __shfl_xor((int)(h ? C1 : D1), 32);
        bf16x8 pa0 = h ? mkfrag(z0, z1, B0, B1) : mkfrag(A0, A1, z0, z1);
        bf16x8 pa1 = h ? mkfrag(z2, z3, D0, D1) : mkfrag(C0, C1, z2, z3);

        A0 = cvtpk(st1[0], st1[1]);   A1 = cvtpk(st1[2], st1[3]);
        B0 = cvtpk(st1[4], st1[5]);   B1 = cvtpk(st1[6], st1[7]);
        C0 = cvtpk(st1[8], st1[9]);   C1 = cvtpk(st1[10], st1[11]);
        D0 = cvtpk(st1[12], st1[13]); D1 = cvtpk(st1[14], st1[15]);
        z0 = __shfl_xor((int)(h ? A0 : B0), 32);
        z1 = __shfl_xor((int)(h ? A1 : B1), 32);
        z2 = __shfl_xor((int)(h ? C0 : D0), 32);
        z3 = __shfl_xor((int)(h ? C1 : D1), 32);
        bf16x8 pa2 = h ? mkfrag(z0, z1, B0, B1) : mkfrag(A0, A1, z0, z1);
        bf16x8 pa3 = h ? mkfrag(z2, z3, D0, D1) : mkfrag(C0, C1, z2, z3);

        // ---- O += P . V  (B-frags from V^T rows; d-tiles 0/1)
        __builtin_amdgcn_s_setprio(1);
        {
            bf16x8 v0 = *(const bf16x8*)(vb + rb0 + koff[0]);
            bf16x8 v1 = *(const bf16x8*)(vb + rb0 + koff[1]);
            bf16x8 v2 = *(const bf16x8*)(vb + rb0 + koff[2]);
            bf16x8 v3 = *(const bf16x8*)(vb + rb0 + koff[3]);
            ok0 = MFMA32(pa0, v0, ok0);
            ok0 = MFMA32(pa1, v1, ok0);
            ok0 = MFMA32(pa2, v2, ok0);
            ok0 = MFMA32(pa3, v3, ok0);
            bf16x8 u0 = *(const bf16x8*)(vb + rb1 + koff[0]);
            bf16x8 u1 = *(const bf16x8*)(vb + rb1 + koff[1]);
            bf16x8 u2 = *(const bf16x8*)(vb + rb1 + koff[2]);
            bf16x8 u3 = *(const bf16x8*)(vb + rb1 + koff[3]);
            ok1 = MFMA32(pa0, u0, ok1);
            ok1 = MFMA32(pa1, u1, ok1);
            ok1 = MFMA32(pa2, u2, ok1);
            ok1 = MFMA32(pa3, u3, ok1);
        }
        __builtin_amdgcn_s_setprio(0);
    };

    #define WAITN(n) asm volatile("s_waitcnt vmcnt(" #n ")" ::: "memory")

    stageA();                                   // tile 0
    stageB();                                   // tile 1
    for (int it = 0; it < 15; ++it) {
        WAITN(4);  __builtin_amdgcn_s_barrier();
        compute(kbA, vbA);                      // tile 2it
        __builtin_amdgcn_s_barrier();
        stageA();                               // tile 2it+2
        WAITN(4);  __builtin_amdgcn_s_barrier();
        compute(kbB, vbB);                      // tile 2it+1
        __builtin_amdgcn_s_barrier();
        stageB();                               // tile 2it+3
    }
    WAITN(4);  __builtin_amdgcn_s_barrier();
    compute(kbA, vbA);                          // tile 30
    WAITN(0);  __builtin_amdgcn_s_barrier();
    compute(kbB, vbB);                          // tile 31
    #undef WAITN

    // ---- epilogue: normalize, write merged bf16 [B, S, DM]
    const float linv = 1.f / lrun;
    const int b = bh >> 3, hh = bh & 7;
    #pragma unroll
    for (int r = 0; r < 16; r++) {
        const int q  = (r & 3) + 8 * (r >> 2) + 4 * h;
        const float li = __shfl(linv, q);
        const int qr = qt * 128 + wid * 32 + q;
        ushort16* orow = O + ((size_t)(b * SEQ + qr)) * DM + hh * DP + l31;
        orow[0]  = f2bf(ok0[r] * li);
        orow[32] = f2bf(ok1[r] * li);
    }
}

// ---------------------------------------------------------------------------
extern "C" void kernel_launch(void* const* d_in, const int* in_sizes, int n_in,
                              void* d_out, int out_size, void* d_ws, size_t ws_size,
                              hipStream_t stream) {
    const float* x  = (const float*)d_in[0];
    const float* Wq = (const float*)d_in[1];
    const float* bq = (const float*)d_in[2];
    const float* Wk = (const float*)d_in[3];
    const float* bk = (const float*)d_in[4];
    const float* Wv = (const float*)d_in[5];
    const float* bv = (const float*)d_in[6];
    const float* Wo = (const float*)d_in[7];
    const float* bo = (const float*)d_in[8];
    float* out = (float*)d_out;

    ushort16* ws   = (ushort16*)d_ws;
    ushort16* xb   = ws;
    ushort16* wqkv = xb + (size_t)MROWS * DM;
    ushort16* wob  = wqkv + (size_t)3 * DM * DM;
    ushort16* qh   = wob + (size_t)DM * DM;
    ushort16* kh   = qh + HEADS_ELEMS;
    ushort16* vt   = kh + HEADS_ELEMS;
    ushort16* oh   = vt + HEADS_ELEMS;

    convert_inputs<<<dim3((XF4 + 4 * WF4) / 256), dim3(256), 0, stream>>>(
        (const float4*)x, (const float4*)Wq, (const float4*)Wk,
        (const float4*)Wv, (const float4*)Wo,
        (ushort4*)xb, (ushort4*)wqkv, (ushort4*)wob);

    gemm_mfma<128, 128, 0><<<dim3(12, 32), dim3(256), 0, stream>>>(
        xb, wqkv, bq, bk, bv, bo, qh, kh, vt, nullptr);

    attn_mfma<<<dim3(256), dim3(256), 0, stream>>>(qh, kh, vt, oh);

    gemm_mfma<64, 128, 1><<<dim3(4, 64), dim3(256), 0, stream>>>(
        oh, wob, bq, bk, bv, bo, qh, kh, vt, out);
}

// Round 7
// 85.840 us; speedup vs baseline: 1.1290x; 1.1290x over previous
//
#include <hip/hip_runtime.h>

typedef unsigned int   uint32;
typedef unsigned short ushort16;

constexpr int BATCH = 2;
constexpr int SEQ   = 2048;
constexpr int DM    = 512;
constexpr int NH    = 8;
constexpr int DP    = 64;
constexpr int MROWS = BATCH * SEQ;                              // 4096
constexpr size_t HEADS_ELEMS = (size_t)BATCH * NH * SEQ * DP;   // 2,097,152

typedef short bf16x8 __attribute__((ext_vector_type(8)));
typedef float f32x4  __attribute__((ext_vector_type(4)));
typedef float f32x16 __attribute__((ext_vector_type(16)));
#define MFMA16(a, b, c) __builtin_amdgcn_mfma_f32_16x16x32_bf16((a), (b), (c), 0, 0, 0)
#define MFMA32(a, b, c) __builtin_amdgcn_mfma_f32_32x32x16_bf16((a), (b), (c), 0, 0, 0)

__device__ __forceinline__ ushort16 f2bf(float f) {
    uint32 u = __float_as_uint(f);
    uint32 r = (u + 0x7fffu + ((u >> 16) & 1u)) >> 16;
    return (ushort16)r;
}

__device__ __forceinline__ uint32 cvtpk(float a, float b) {
    uint32 r;
    asm("v_cvt_pk_bf16_f32 %0, %1, %2" : "=v"(r) : "v"(a), "v"(b));
    return r;
}

__device__ __forceinline__ bf16x8 mkfrag(uint32 u0, uint32 u1, uint32 u2, uint32 u3) {
    union { uint32 u[4]; bf16x8 v; } t;
    t.u[0] = u0; t.u[1] = u1; t.u[2] = u2; t.u[3] = u3;
    return t.v;
}

__device__ __forceinline__ void gload16(const void* g, void* l) {
    __builtin_amdgcn_global_load_lds(
        (const __attribute__((address_space(1))) unsigned int*)g,
        (__attribute__((address_space(3))) unsigned int*)l, 16, 0, 0);
}

// ---------------------------------------------------------------------------
// Convert fp32 inputs to bf16 working buffers.
// ---------------------------------------------------------------------------
constexpr int XF4 = (MROWS * DM) / 4;   // 524288
constexpr int WF4 = (DM * DM) / 4;      // 65536

__global__ __launch_bounds__(256)
void convert_inputs(const float4* __restrict__ x,  const float4* __restrict__ wq,
                    const float4* __restrict__ wk, const float4* __restrict__ wv,
                    const float4* __restrict__ wo, ushort4* __restrict__ xb,
                    ushort4* __restrict__ wqkv, ushort4* __restrict__ wob) {
    const int idx = blockIdx.x * 256 + threadIdx.x;
    float4 v; ushort4* dp;
    if (idx < XF4) { v = x[idx]; dp = xb + idx; }
    else {
        const int r = idx - XF4;
        if (r < WF4)          { v = wq[r];           dp = wqkv + r; }
        else if (r < 2 * WF4) { v = wk[r - WF4];     dp = wqkv + r; }
        else if (r < 3 * WF4) { v = wv[r - 2 * WF4]; dp = wqkv + r; }
        else                  { v = wo[r - 3 * WF4]; dp = wob + (r - 3 * WF4); }
    }
    ushort4 o = {f2bf(v.x), f2bf(v.y), f2bf(v.z), f2bf(v.w)};
    *dp = o;
}

// ---------------------------------------------------------------------------
// bf16 MFMA GEMM (unchanged; correctness-verified).
// ---------------------------------------------------------------------------
template <int BM, int BN, int EPI>
__global__ __launch_bounds__(256)
void gemm_mfma(const ushort16* __restrict__ X, const ushort16* __restrict__ Wc,
               const float* __restrict__ bq_, const float* __restrict__ bk_,
               const float* __restrict__ bv_, const float* __restrict__ bo_,
               ushort16* __restrict__ Qh, ushort16* __restrict__ Kh,
               ushort16* __restrict__ Vt, float* __restrict__ Out) {
    constexpr int FM = BM / 32;
    constexpr int FN = BN / 32;
    __shared__ ushort16 As[BM * 32];
    __shared__ ushort16 Bs[BN * 32];

    const int tid  = threadIdx.x;
    const int lane = tid & 63;
    const int wid  = tid >> 6;
    const int lg   = lane >> 4;
    const int lq   = lane & 15;
    const int wr   = wid >> 1;
    const int wc   = wid & 1;
    const int m0   = blockIdx.y * BM;
    const int n0   = blockIdx.x * BN;
    const bool swapped = (EPI == 1) || (n0 < 2 * DM);

    f32x4 acc[FM][FN];
    #pragma unroll
    for (int i = 0; i < FM; i++)
        #pragma unroll
        for (int j = 0; j < FN; j++)
            #pragma unroll
            for (int r = 0; r < 4; r++) acc[i][j][r] = 0.f;

    for (int k0 = 0; k0 < DM; k0 += 32) {
        #pragma unroll
        for (int i = 0; i < BM / 64; i++) {
            const int ch = tid + i * 256;
            const int row = ch >> 2, c8 = (ch & 3) * 8;
            gload16(X + (size_t)(m0 + row) * DM + k0 + c8, As + (size_t)ch * 8);
        }
        #pragma unroll
        for (int i = 0; i < BN / 64; i++) {
            const int ch = tid + i * 256;
            const int row = ch >> 2, c8 = (ch & 3) * 8;
            gload16(Wc + (size_t)(n0 + row) * DM + k0 + c8, Bs + (size_t)ch * 8);
        }
        __syncthreads();

        bf16x8 af[FM], bfr[FN];
        #pragma unroll
        for (int i = 0; i < FM; i++)
            af[i] = *(const bf16x8*)(As + (size_t)(wr * (BM / 2) + i * 16 + lq) * 32 + lg * 8);
        #pragma unroll
        for (int j = 0; j < FN; j++)
            bfr[j] = *(const bf16x8*)(Bs + (size_t)(wc * (BN / 2) + j * 16 + lq) * 32 + lg * 8);

        if (swapped) {
            #pragma unroll
            for (int i = 0; i < FM; i++)
                #pragma unroll
                for (int j = 0; j < FN; j++)
                    acc[i][j] = MFMA16(bfr[j], af[i], acc[i][j]);
        } else {
            #pragma unroll
            for (int i = 0; i < FM; i++)
                #pragma unroll
                for (int j = 0; j < FN; j++)
                    acc[i][j] = MFMA16(af[i], bfr[j], acc[i][j]);
        }
        __syncthreads();
    }

    if (EPI == 1) {
        #pragma unroll
        for (int i = 0; i < FM; i++) {
            const int m = m0 + wr * (BM / 2) + i * 16 + lq;
            #pragma unroll
            for (int j = 0; j < FN; j++) {
                const int nr = n0 + wc * (BN / 2) + j * 16 + lg * 4;
                float4 b4 = *(const float4*)(bo_ + nr);
                float4 o;
                o.x = acc[i][j][0] + b4.x; o.y = acc[i][j][1] + b4.y;
                o.z = acc[i][j][2] + b4.z; o.w = acc[i][j][3] + b4.w;
                *(float4*)(Out + (size_t)m * DM + nr) = o;
            }
        }
    } else if (n0 < 2 * DM) {
        #pragma unroll
        for (int i = 0; i < FM; i++) {
            const int m = m0 + wr * (BM / 2) + i * 16 + lq;
            const int b = m >> 11, s = m & (SEQ - 1);
            #pragma unroll
            for (int j = 0; j < FN; j++) {
                const int nr = n0 + wc * (BN / 2) + j * 16 + lg * 4;
                const bool isq = nr < DM;
                const int rel = nr & (DM - 1);
                const int h = rel >> 6, d = rel & 63;
                float4 b4 = *(const float4*)((isq ? bq_ : bk_) + rel);
                const float sc = isq ? 0.125f : 1.0f;
                ushort4 o = { f2bf((acc[i][j][0] + b4.x) * sc),
                              f2bf((acc[i][j][1] + b4.y) * sc),
                              f2bf((acc[i][j][2] + b4.z) * sc),
                              f2bf((acc[i][j][3] + b4.w) * sc) };
                ushort16* dst = (isq ? Qh : Kh) +
                    (((size_t)(b * NH + h) * SEQ + s) * DP + d);
                *(ushort4*)dst = o;
            }
        }
    } else {
        #pragma unroll
        for (int j = 0; j < FN; j++) {
            const int n = n0 + wc * (BN / 2) + j * 16 + lq;
            const int rel = n - 2 * DM;
            const int h = rel >> 6, d = rel & 63;
            const float bias = bv_[rel];
            #pragma unroll
            for (int i = 0; i < FM; i++) {
                const int mr = m0 + wr * (BM / 2) + i * 16 + lg * 4;
                const int b = mr >> 11, s0 = mr & (SEQ - 1);
                ushort4 o = { f2bf(acc[i][j][0] + bias),
                              f2bf(acc[i][j][1] + bias),
                              f2bf(acc[i][j][2] + bias),
                              f2bf(acc[i][j][3] + bias) };
                ushort16* dst = Vt +
                    (((size_t)(b * NH + h) * DP + d) * SEQ + s0);
                *(ushort4*)dst = o;
            }
        }
    }
}

// ---------------------------------------------------------------------------
// MFMA bf16 flash attention v5 (8-wave split-k, 32x32 shapes).
// Grid 256 (XCD-swizzled, 1 block/CU): block = 128 q-rows of one (b,h).
// 512 thr = 8 waves = 4 q-subtiles (32 rows) x 2 k-halves (32 of each 64-tile).
// -> 2 waves/SIMD: one wave's softmax overlaps the partner's MFMA.
// Per wave/tile: 4 QK^T MFMA32 + 4 PV MFMA32; P stays in registers
// (cvt_pk + shfl_xor(32)); counted vmcnt(2); defer-max THR=8.
// End: (m,l,O) split-k merge through reused LDS.
// ---------------------------------------------------------------------------
__global__ __launch_bounds__(512, 1)
void attn_mfma(const ushort16* __restrict__ Q, const ushort16* __restrict__ K,
               const ushort16* __restrict__ Vt, ushort16* __restrict__ O) {
    __shared__ ushort16 Kl[2][64 * 64];     // 16 KB
    __shared__ ushort16 Vl[2][64 * 64];     // 16 KB
    __shared__ float    mlbuf[4][2][32];    // 1 KB

    const int tid  = threadIdx.x;
    const int lane = tid & 63;
    const int wid  = tid >> 6;       // 0..7
    const int qw   = wid & 3;        // q-subtile (32 rows)
    const int kw   = wid >> 2;       // k-half (32 of each 64-tile)
    const int h    = lane >> 5;
    const int l31  = lane & 31;
    const int l7   = l31 & 7;

    const int bid = blockIdx.x;                   // 0..255
    const int w   = (bid & 7) * 32 + (bid >> 3);  // 8 XCDs x 32
    const int qt  = w & 15;                       // q-tile (128 rows)
    const int bh  = w >> 4;                       // head 0..15

    // Q fragments (B-operand: col q=l31, depth elems h*8+j per 16-step)
    const int qrow = qt * 128 + qw * 32 + l31;
    const ushort16* qbase = Q + ((size_t)bh * SEQ + qrow) * DP;
    bf16x8 qf[4];
    #pragma unroll
    for (int ds = 0; ds < 4; ds++)
        qf[ds] = *(const bf16x8*)(qbase + ds * 16 + h * 8);

    f32x16 ok0, ok1;
    #pragma unroll
    for (int r = 0; r < 16; r++) { ok0[r] = 0.f; ok1[r] = 0.f; }
    float mrun = -1e30f, lrun = 0.f;

    // ---- staging: 512 thr, one 16B chunk each per matrix per tile ----
    const ushort16* kg = K  + (size_t)bh * SEQ * DP;   // [2048][64]
    const ushort16* vg = Vt + (size_t)bh * DP * SEQ;   // [64][2048]
    const int r0 = tid >> 3, c0 = tid & 7;
    const int sc0 = (c0 ^ (r0 & 7)) * 8;               // inverse-swizzled src col
    const ushort16* kp = kg + (size_t)r0 * DP + sc0;
    const ushort16* vp = vg + (size_t)r0 * SEQ + sc0;
    ushort16* const kA = &Kl[0][(size_t)tid * 8];
    ushort16* const kB = &Kl[1][(size_t)tid * 8];
    ushort16* const vA = &Vl[0][(size_t)tid * 8];
    ushort16* const vB = &Vl[1][(size_t)tid * 8];

    auto stageA = [&]() {
        gload16(kp, kA); gload16(vp, vA);
        kp += 64 * DP; vp += 64;
    };
    auto stageB = [&]() {
        gload16(kp, kB); gload16(vp, vB);
        kp += 64 * DP; vp += 64;
    };

    // hoisted swizzled read offsets
    const int krb = (kw * 32 + l31) * 64;        // K row base (this wave's k-half)
    int koff[4];
    #pragma unroll
    for (int ds = 0; ds < 4; ds++)
        koff[ds] = krb + (((ds * 2 + h) ^ l7) * 8);
    int voff[2][2];                               // [d-tile][kc]
    #pragma unroll
    for (int dt = 0; dt < 2; dt++)
        #pragma unroll
        for (int kc = 0; kc < 2; kc++)
            voff[dt][kc] = (dt * 32 + l31) * 64 + (((kw * 4 + kc * 2 + h) ^ l7) * 8);

    const ushort16* const kbA = &Kl[0][0];
    const ushort16* const kbB = &Kl[1][0];
    const ushort16* const vbA = &Vl[0][0];
    const ushort16* const vbB = &Vl[1][0];

    auto compute = [&](const ushort16* kb, const ushort16* vb) {
        // S^T for this wave's 32-k half: st[r] = S[q=l31][k=(r&3)+8*(r>>2)+4*h]
        f32x16 st;
        #pragma unroll
        for (int r = 0; r < 16; r++) st[r] = 0.f;
        __builtin_amdgcn_s_setprio(1);
        #pragma unroll
        for (int ds = 0; ds < 4; ds++) {
            bf16x8 kf = *(const bf16x8*)(kb + koff[ds]);
            st = MFMA32(kf, qf[ds], st);
        }
        __builtin_amdgcn_s_setprio(0);

        // online softmax (lane-local q, halves merged via shfl_xor 32)
        float tmax = st[0];
        #pragma unroll
        for (int r = 1; r < 16; r++) tmax = fmaxf(tmax, st[r]);
        tmax = fmaxf(tmax, __shfl_xor(tmax, 32));

        if (!__all(tmax <= mrun + 8.f)) {       // defer-max, rare
            const float mnew = fmaxf(mrun, tmax);
            const float corr = __expf(mrun - mnew);
            #pragma unroll
            for (int r = 0; r < 16; r++) {
                const float c = __shfl(corr, (r & 3) + 8 * (r >> 2) + 4 * h);
                ok0[r] *= c; ok1[r] *= c;
            }
            lrun *= corr;
            mrun = mnew;
        }

        float psum = 0.f;
        #pragma unroll
        for (int r = 0; r < 16; r++) {
            st[r] = __expf(st[r] - mrun); psum += st[r];
        }
        psum += __shfl_xor(psum, 32);
        lrun += psum;

        // pack P -> bf16 A-fragments (cvt_pk + half-swap)
        uint32 A0 = cvtpk(st[0], st[1]),   A1 = cvtpk(st[2], st[3]);
        uint32 B0 = cvtpk(st[4], st[5]),   B1 = cvtpk(st[6], st[7]);
        uint32 C0 = cvtpk(st[8], st[9]),   C1 = cvtpk(st[10], st[11]);
        uint32 D0 = cvtpk(st[12], st[13]), D1 = cvtpk(st[14], st[15]);
        uint32 z0 = __shfl_xor((int)(h ? A0 : B0), 32);
        uint32 z1 = __shfl_xor((int)(h ? A1 : B1), 32);
        uint32 z2 = __shfl_xor((int)(h ? C0 : D0), 32);
        uint32 z3 = __shfl_xor((int)(h ? C1 : D1), 32);
        bf16x8 pa0 = h ? mkfrag(z0, z1, B0, B1) : mkfrag(A0, A1, z0, z1);  // kc=0
        bf16x8 pa1 = h ? mkfrag(z2, z3, D0, D1) : mkfrag(C0, C1, z2, z3);  // kc=1

        // O += P . V
        const bf16x8 v00 = *(const bf16x8*)(vb + voff[0][0]);
        const bf16x8 v01 = *(const bf16x8*)(vb + voff[0][1]);
        const bf16x8 v10 = *(const bf16x8*)(vb + voff[1][0]);
        const bf16x8 v11 = *(const bf16x8*)(vb + voff[1][1]);
        __builtin_amdgcn_s_setprio(1);
        ok0 = MFMA32(pa0, v00, ok0);
        ok0 = MFMA32(pa1, v01, ok0);
        ok1 = MFMA32(pa0, v10, ok1);
        ok1 = MFMA32(pa1, v11, ok1);
        __builtin_amdgcn_s_setprio(0);
    };

    #define WAITN(n) asm volatile("s_waitcnt vmcnt(" #n ")" ::: "memory")

    stageA();                                   // tile 0
    stageB();                                   // tile 1
    for (int it = 0; it < 15; ++it) {
        WAITN(2);  __builtin_amdgcn_s_barrier();
        compute(kbA, vbA);                      // tile 2it
        __builtin_amdgcn_s_barrier();
        stageA();                               // tile 2it+2
        WAITN(2);  __builtin_amdgcn_s_barrier();
        compute(kbB, vbB);                      // tile 2it+1
        __builtin_amdgcn_s_barrier();
        stageB();                               // tile 2it+3
    }
    WAITN(2);  __builtin_amdgcn_s_barrier();
    compute(kbA, vbA);                          // tile 30
    WAITN(0);  __builtin_amdgcn_s_barrier();
    compute(kbB, vbB);                          // tile 31
    #undef WAITN

    // ---- split-k merge: kw=1 dumps partials (reusing K/V LDS), kw=0 combines
    __syncthreads();
    float* const obase = (qw < 2) ? ((float*)&Kl[0][0] + qw * 2048)
                                  : ((float*)&Vl[0][0] + (qw - 2) * 2048);
    if (kw == 1) {
        #pragma unroll
        for (int r = 0; r < 16; r++) {
            const int q = (r & 3) + 8 * (r >> 2) + 4 * h;
            obase[q * 64 + l31]      = ok0[r];
            obase[q * 64 + 32 + l31] = ok1[r];
        }
        if (h == 0) {
            mlbuf[qw][0][l31] = mrun;
            mlbuf[qw][1][l31] = lrun;
        }
    }
    __syncthreads();
    if (kw == 0) {
        const float mb = mlbuf[qw][0][l31];
        const float lb = mlbuf[qw][1][l31];
        const float ms = fmaxf(mrun, mb);
        const float fa = __expf(mrun - ms);
        const float fb = __expf(mb - ms);
        const float linv = 1.f / (lrun * fa + lb * fb);

        const int b = bh >> 3, hh = bh & 7;
        #pragma unroll
        for (int r = 0; r < 16; r++) {
            const int q = (r & 3) + 8 * (r >> 2) + 4 * h;
            const float fa_q = __shfl(fa, q);
            const float fb_q = __shfl(fb, q);
            const float li_q = __shfl(linv, q);
            const float v0 = (ok0[r] * fa_q + obase[q * 64 + l31] * fb_q) * li_q;
            const float v1 = (ok1[r] * fa_q + obase[q * 64 + 32 + l31] * fb_q) * li_q;
            const int qr = qt * 128 + qw * 32 + q;
            ushort16* orow = O + ((size_t)(b * SEQ + qr)) * DM + hh * DP;
            orow[l31]      = f2bf(v0);
            orow[32 + l31] = f2bf(v1);
        }
    }
}

// ---------------------------------------------------------------------------
extern "C" void kernel_launch(void* const* d_in, const int* in_sizes, int n_in,
                              void* d_out, int out_size, void* d_ws, size_t ws_size,
                              hipStream_t stream) {
    const float* x  = (const float*)d_in[0];
    const float* Wq = (const float*)d_in[1];
    const float* bq = (const float*)d_in[2];
    const float* Wk = (const float*)d_in[3];
    const float* bk = (const float*)d_in[4];
    const float* Wv = (const float*)d_in[5];
    const float* bv = (const float*)d_in[6];
    const float* Wo = (const float*)d_in[7];
    const float* bo = (const float*)d_in[8];
    float* out = (float*)d_out;

    ushort16* ws   = (ushort16*)d_ws;
    ushort16* xb   = ws;
    ushort16* wqkv = xb + (size_t)MROWS * DM;
    ushort16* wob  = wqkv + (size_t)3 * DM * DM;
    ushort16* qh   = wob + (size_t)DM * DM;
    ushort16* kh   = qh + HEADS_ELEMS;
    ushort16* vt   = kh + HEADS_ELEMS;
    ushort16* oh   = vt + HEADS_ELEMS;

    convert_inputs<<<dim3((XF4 + 4 * WF4) / 256), dim3(256), 0, stream>>>(
        (const float4*)x, (const float4*)Wq, (const float4*)Wk,
        (const float4*)Wv, (const float4*)Wo,
        (ushort4*)xb, (ushort4*)wqkv, (ushort4*)wob);

    gemm_mfma<128, 128, 0><<<dim3(12, 32), dim3(256), 0, stream>>>(
        xb, wqkv, bq, bk, bv, bo, qh, kh, vt, nullptr);

    attn_mfma<<<dim3(256), dim3(512), 0, stream>>>(qh, kh, vt, oh);

    gemm_mfma<64, 128, 1><<<dim3(4, 64), dim3(256), 0, stream>>>(
        oh, wob, bq, bk, bv, bo, qh, kh, vt, out);
}